// Round 10
// baseline (218.850 us; speedup 1.0000x reference)
//
#include <hip/hip_runtime.h>

// WinGNN: conv-encode (fp16 MFMA, B-in-LDS, 4-chain, 4-waves/SIMD occupancy) ->
// radius-KNN -> 4-layer GNN (fp16 MFMA, agg fused into GEMM staging).
//
// Workspace layout (bytes):
//   wfrag @ 0        : 11264 fp16 conv-weight fragments, 22 granules (32768 B slot)
//   enc   @ 32768    : 2048x64 f32 (524288)  [zeroed in setup, accumulated via atomics]
//   h16a  @ 557056   : 2048x512 fp16 (2 MB)
//   h16b  @ 2654208  : 2048x512 fp16 (2 MB)
//   wT16  @ 6848512  : 8x512x512 fp16 (4 MB)
//   nbr   @ 11042816 : 2048x5 int (40960 slot)
//   den   @ 11083776 : 2048 f32 (stores 1/count)

#define NNODES 2048

typedef __attribute__((ext_vector_type(8))) _Float16 half8;
typedef __attribute__((ext_vector_type(16))) float f32x16;

__device__ inline uint pack2h(float x, float y) {
  ushort a = __builtin_bit_cast(ushort, (_Float16)x);
  ushort b = __builtin_bit_cast(ushort, (_Float16)y);
  return (uint)a | ((uint)b << 16);
}

// ---------- setup: wfrag prep (44 blocks) | wT prep (512) | knn + enc zero (2048) ----------
__global__ __launch_bounds__(256) void setup_kernel(
    const float* __restrict__ conv_w, const float* __restrict__ wsrc_s,
    const float* __restrict__ wsrc_n, const float* __restrict__ pos,
    ushort* __restrict__ wfrag, ushort* __restrict__ wT,
    int* __restrict__ nbr, float* __restrict__ den, float* __restrict__ enc) {
  __shared__ float4 smem4[1040];        // 16640 B, unioned per role
  const int bid = blockIdx.x;
  const int tid = threadIdx.x;

  if (bid < 44) {
    // conv_w [64][3][7][7] -> B-fragments: (((ct*11+kb)*64+lane)*8+j), 11264 total
    int i = bid * 256 + tid;
    int j = i & 7;
    int l = (i >> 3) & 63;
    int q = i >> 9;            // ct*11 + kb
    int kb = q % 11, ct = q / 11;
    int g = 2 * kb + (l >> 5);
    int c = 32 * ct + (l & 31);
    float val = 0.f;
    if (g < 21 && j < 7) val = conv_w[c * 147 + g * 7 + j];
    wfrag[i] = __builtin_bit_cast(ushort, (_Float16)val);
    return;
  }

  if (bid < 556) {
    // w_self/w_nbr [k][n] f32 -> wT16 [m][n][k] fp16
    float(*s)[65] = (float(*)[65])smem4;
    int bid2 = bid - 44;
    int m = bid2 >> 6, kt = (bid2 >> 3) & 7, nt = bid2 & 7;
    const float* in = (m < 4) ? (wsrc_s + m * 262144) : (wsrc_n + (m - 4) * 262144);
    ushort* out = wT + m * 262144;
    int k0 = kt << 6, n0 = nt << 6;
#pragma unroll
    for (int rep = 0; rep < 4; ++rep) {
      int row = (rep << 4) + (tid >> 4);
      int c4 = (tid & 15) << 2;
      float4 v = *(const float4*)&in[(k0 + row) * 512 + n0 + c4];
      s[row][c4] = v.x; s[row][c4 + 1] = v.y; s[row][c4 + 2] = v.z; s[row][c4 + 3] = v.w;
    }
    __syncthreads();
#pragma unroll
    for (int rep = 0; rep < 4; ++rep) {
      int n = (rep << 4) + (tid >> 4);
      int k4 = (tid & 15) << 2;
      ushort4 o;
      o.x = __builtin_bit_cast(ushort, (_Float16)s[k4 + 0][n]);
      o.y = __builtin_bit_cast(ushort, (_Float16)s[k4 + 1][n]);
      o.z = __builtin_bit_cast(ushort, (_Float16)s[k4 + 2][n]);
      o.w = __builtin_bit_cast(ushort, (_Float16)s[k4 + 3][n]);
      *(ushort4*)&out[(n0 + n) * 512 + k0 + k4] = o;
    }
    return;
  }

  // radius-KNN for node i; also zero enc rows for conv's atomicAdd
  {
    float* s_d2 = (float*)smem4;
    int* s_idx = (int*)(s_d2 + NNODES);
    int* s_cnt = (int*)(s_idx + NNODES);
    const int i = bid - 556;
    if (tid < 16) {
      float4 z4 = {0.f, 0.f, 0.f, 0.f};
      ((float4*)(enc + i * 64))[tid] = z4;
    }
    if (tid == 0) *s_cnt = 0;
    __syncthreads();
    const float px = pos[2 * i] * 32.f, py = pos[2 * i + 1] * 32.f;
#pragma unroll
    for (int r = 0; r < 8; ++r) {
      int j = tid + (r << 8);
      float2 q = ((const float2*)pos)[j];
      float dx = q.x * 32.f - px, dy = q.y * 32.f - py;
      float d2 = dx * dx + dy * dy;
      if (d2 <= 2.0f && j != i) {
        int slot = atomicAdd(s_cnt, 1);
        s_d2[slot] = d2;
        s_idx[slot] = j;
      }
    }
    __syncthreads();
    if (tid < 64) {
      const int lane = tid;
      const int cnt = *s_cnt;
      int nf = 0;
#pragma unroll
      for (int k = 0; k < 5; ++k) {
        float best = 1e30f;
        int bslot = 0x7fffffff;
        for (int e = lane; e < cnt; e += 64) {
          float d = s_d2[e];
          if (d < best) { best = d; bslot = e; }
        }
#pragma unroll
        for (int off = 1; off < 64; off <<= 1) {
          float od = __shfl_xor(best, off);
          int os = __shfl_xor(bslot, off);
          if (od < best || (od == best && os < bslot)) { best = od; bslot = os; }
        }
        bool got = (best < 1e30f);
        if (lane == 0) nbr[i * 5 + k] = got ? s_idx[bslot] : -1;
        if (got) { s_d2[bslot] = 1e30f; ++nf; }
      }
      if (lane == 0) den[i] = 1.f / (float)(nf > 0 ? nf : 1);
    }
  }
}

// ---------- conv7x7 s2 SAME + bias + relu + avg pool, fp16 MFMA ----------
// 2 blocks/image (16 out rows), 4 waves, wave = 2 rows x 2 ch-tiles x 2 tp,
// 64 AGPR acc + ~55 VGPR -> 4 waves/SIMD; LDS 39.5 KB -> 4 blocks/CU.
// A-addressing: one base reg + compile-time offsets (kb=3 gets its own reg;
// kb=10/hi=1 granule has zero B so its A-read is in-bounds garbage).
// LDS: image [3][37][72] fp16 @0 (15984) | wfrag @15984 (22528) | pool @38512 (1024)
__global__ __launch_bounds__(256, 4) void conv_pool_kernel(
    const float* __restrict__ imgs, const ushort* __restrict__ wfrag,
    const float* __restrict__ cb, float* __restrict__ enc) {
  __shared__ int4 s_all[2471];          // 39536 B
  ushort* s_img = (ushort*)s_all;
  float* s_pool = (float*)((char*)s_all + 38512);

  const int n = blockIdx.x >> 1;
  const int r0half = blockIdx.x & 1;
  const int wy = 32 * r0half - 2;
  const int tid = threadIdx.x;
  const int lane = tid & 63;
  const int w = tid >> 6;
  const int hi = lane >> 5;
  const int lo = lane & 31;

  // zero image region
  int4 z = {0, 0, 0, 0};
  for (int i = tid; i < 999; i += 256) s_all[i] = z;

  // stage wfrag -> LDS via global_load_lds (22528 B = 1408 int4)
  {
    char* ldsb = (char*)s_all + 15984;
#pragma unroll
    for (int r = 0; r < 5; ++r) {
      __builtin_amdgcn_global_load_lds(
          (const __attribute__((address_space(1))) void*)(wfrag + (r * 256 + tid) * 8),
          (__attribute__((address_space(3))) void*)(ldsb + (r * 256 + tid) * 16), 16, 0, 0);
    }
    if (tid < 128) {
      __builtin_amdgcn_global_load_lds(
          (const __attribute__((address_space(1))) void*)(wfrag + (1280 + tid) * 8),
          (__attribute__((address_space(3))) void*)(ldsb + (1280 + tid) * 16), 16, 0, 0);
    }
  }
  __syncthreads();   // zeros + wfrag complete

  // stage image window fp32 -> fp16 LDS
  const float4* src = (const float4*)(imgs + (size_t)n * 12288);
  for (int i = tid; i < 1776; i += 256) {
    int ic = i / 592;
    int rem = i - ic * 592;
    int li = rem >> 4, xq = rem & 15;
    int iy = wy + li;
    if (iy >= 0 && iy < 64) {
      float4 v = src[(ic * 64 + iy) * 16 + xq];
      int d = (ic * 37 + li) * 72 + (xq << 2) + 2;
      ((uint*)s_img)[d >> 1] = pack2h(v.x, v.y);
      ((uint*)s_img)[(d >> 1) + 1] = pack2h(v.z, v.w);
    }
  }

  const float bias0 = cb[lo];
  const float bias1 = cb[32 + lo];
  __syncthreads();

  // base addresses (byte offsets into LDS)
  const char* sb = (const char*)s_img;
  const char* baseA = sb + 4 * lo + w * 1152 + (hi ? 144 : 0);   // all kb != 3
  const char* baseA3 = sb + 4 * lo + w * 1152 + (hi ? 5328 : 864); // kb == 3
  const char* baseB = (const char*)s_all + 15984 + lane * 16;

  // compile-time A offsets per kb (row(2kb)*144); kb=3 handled via baseA3
  // kb:      0    1    2     3     4     5     6      7      8      9     10
  // off:     0  288  576    (0) 5472  5760  6048  10656  10944  11232  11520

  union F { half8 v; uint u[4]; };
  float poolacc0 = 0.f, poolacc1 = 0.f;

#define LOADA(F0, F1, BASE, OFF, TP) do {                                     \
    const uint* p_ = (const uint*)((BASE) + (OFF) + (TP) * 576);              \
    F0.u[0] = p_[0]; F0.u[1] = p_[1]; F0.u[2] = p_[2]; F0.u[3] = p_[3];       \
    const uint* q_ = (const uint*)((BASE) + (OFF) + (TP) * 576 + 288);        \
    F1.u[0] = q_[0]; F1.u[1] = q_[1]; F1.u[2] = q_[2]; F1.u[3] = q_[3];       \
  } while (0)
#define LOADB(B0, B1, KB) do {                                                \
    B0 = *(const half8*)(baseB + (KB) * 1024);                                \
    B1 = *(const half8*)(baseB + 11264 + (KB) * 1024);                        \
  } while (0)
#define MFMA4(FF0, FF1, BB0, BB1) do {                                        \
    __builtin_amdgcn_s_setprio(1);                                            \
    a0 = __builtin_amdgcn_mfma_f32_32x32x16_f16(FF0.v, BB0, a0, 0, 0, 0);     \
    a1 = __builtin_amdgcn_mfma_f32_32x32x16_f16(FF0.v, BB1, a1, 0, 0, 0);     \
    a2 = __builtin_amdgcn_mfma_f32_32x32x16_f16(FF1.v, BB0, a2, 0, 0, 0);     \
    a3 = __builtin_amdgcn_mfma_f32_32x32x16_f16(FF1.v, BB1, a3, 0, 0, 0);     \
    __builtin_amdgcn_s_setprio(0);                                            \
  } while (0)

#pragma unroll
  for (int tp = 0; tp < 2; ++tp) {
    f32x16 a0 = {}, a1 = {}, a2 = {}, a3 = {};
    F f0a, f1a, f0b, f1b;
    half8 b0a, b1a, b0b, b1b;
    LOADA(f0a, f1a, baseA, 0, tp);        LOADB(b0a, b1a, 0);
    LOADA(f0b, f1b, baseA, 288, tp);      LOADB(b0b, b1b, 1);
    MFMA4(f0a, f1a, b0a, b1a);
    LOADA(f0a, f1a, baseA, 576, tp);      LOADB(b0a, b1a, 2);
    MFMA4(f0b, f1b, b0b, b1b);
    LOADA(f0b, f1b, baseA3, 0, tp);       LOADB(b0b, b1b, 3);
    MFMA4(f0a, f1a, b0a, b1a);
    LOADA(f0a, f1a, baseA, 5472, tp);     LOADB(b0a, b1a, 4);
    MFMA4(f0b, f1b, b0b, b1b);
    LOADA(f0b, f1b, baseA, 5760, tp);     LOADB(b0b, b1b, 5);
    MFMA4(f0a, f1a, b0a, b1a);
    LOADA(f0a, f1a, baseA, 6048, tp);     LOADB(b0a, b1a, 6);
    MFMA4(f0b, f1b, b0b, b1b);
    LOADA(f0b, f1b, baseA, 10656, tp);    LOADB(b0b, b1b, 7);
    MFMA4(f0a, f1a, b0a, b1a);
    LOADA(f0a, f1a, baseA, 10944, tp);    LOADB(b0a, b1a, 8);
    MFMA4(f0b, f1b, b0b, b1b);
    LOADA(f0b, f1b, baseA, 11232, tp);    LOADB(b0b, b1b, 9);
    MFMA4(f0a, f1a, b0a, b1a);
    LOADA(f0a, f1a, baseA, 11520, tp);    LOADB(b0a, b1a, 10);
    MFMA4(f0b, f1b, b0b, b1b);
    MFMA4(f0a, f1a, b0a, b1a);

    float s0 = 0.f, s1 = 0.f;
#pragma unroll
    for (int r = 0; r < 16; ++r) {
      s0 += fmaxf(a0[r] + bias0, 0.f) + fmaxf(a2[r] + bias0, 0.f);
      s1 += fmaxf(a1[r] + bias1, 0.f) + fmaxf(a3[r] + bias1, 0.f);
    }
    poolacc0 += s0;
    poolacc1 += s1;
  }
#undef LOADA
#undef LOADB
#undef MFMA4

  poolacc0 += __shfl_xor(poolacc0, 32);
  poolacc1 += __shfl_xor(poolacc1, 32);
  if (lane < 32) {
    s_pool[w * 64 + lo] = poolacc0;
    s_pool[w * 64 + 32 + lo] = poolacc1;
  }
  __syncthreads();
  if (tid < 64) {
    float s = s_pool[tid] + s_pool[64 + tid] + s_pool[128 + tid] + s_pool[192 + tid];
    atomicAdd(&enc[n * 64 + tid], s * (1.f / 1024.f));   // 2 addends: commutative
  }
}

// ---------- proj: relu(enc @ pw + pb) -> h16 [2048][512] fp16 ----------
__global__ __launch_bounds__(256) void proj_kernel(
    const float* __restrict__ enc, const float* __restrict__ pw,
    const float* __restrict__ pb, ushort* __restrict__ h16) {
  int c = ((blockIdx.x & 1) << 8) | threadIdx.x;
  int r0 = (blockIdx.x >> 1) << 3;
  float bias = pb[c];
  float acc[8];
#pragma unroll
  for (int r = 0; r < 8; ++r) acc[r] = bias;
#pragma unroll 4
  for (int k = 0; k < 64; ++k) {
    float w = pw[k * 512 + c];
#pragma unroll
    for (int r = 0; r < 8; ++r) acc[r] = fmaf(enc[(r0 + r) * 64 + k], w, acc[r]);
  }
#pragma unroll
  for (int r = 0; r < 8; ++r)
    h16[(r0 + r) * 512 + c] = __builtin_bit_cast(ushort, (_Float16)fmaxf(acc[r], 0.f));
}

// ---------- GNN layer: out = relu(h@Ws + mean_nbr(h)@Wn + b), agg fused ----------
__global__ __launch_bounds__(256) void gnn_gemm_kernel(
    const ushort* __restrict__ h16, const int* __restrict__ nbr,
    const float* __restrict__ den,
    const ushort* __restrict__ Ws, const ushort* __restrict__ Wn,
    const float* __restrict__ bias, ushort* __restrict__ hout,
    float* __restrict__ fout, int final_layer) {
  __shared__ ushort s_lds[2][16384];
  __shared__ int s_nbr[320];
  __shared__ float s_den[64];
  const int tid = threadIdx.x;
  const int lane = tid & 63;
  const int hi = lane >> 5, lo = lane & 31;
  const int wu = __builtin_amdgcn_readfirstlane(tid >> 6);
  const int wr = wu >> 1, wc = wu & 1;
  const int bm = blockIdx.x >> 3, bn = blockIdx.x & 7;
  const int r0 = bm << 6, c0 = bn << 6;

  if (tid < 80) ((int4*)s_nbr)[tid] = ((const int4*)(nbr + r0 * 5))[tid];
  else if (tid < 96) ((float4*)s_den)[tid - 80] = ((const float4*)(den + r0))[tid - 80];
  __syncthreads();

  const int grow = tid >> 2, gseg = tid & 3;
  int gj[5];
  uint gm[5];
#pragma unroll
  for (int k = 0; k < 5; ++k) {
    int j = s_nbr[grow * 5 + k];
    gm[k] = (j >= 0) ? 0xFFFFFFFFu : 0u;
    gj[k] = (j >= 0) ? j : 0;
  }
  half8 den8;
  {
    _Float16 dh = (_Float16)s_den[grow];
#pragma unroll
    for (int e = 0; e < 8; ++e) den8[e] = dh;
  }

  union GU { half8 v; uint u[4]; };
  GU ga[5][2];

  auto GATHER = [&](int it) {
    const ushort* hb = h16 + (it << 6) + gseg * 16;
#pragma unroll
    for (int k = 0; k < 5; ++k) {
      const half8* p = (const half8*)(hb + gj[k] * 512);
      ga[k][0].v = p[0];
      ga[k][1].v = p[1];
    }
  };
  auto COMBINE = [&](int buf) {
#pragma unroll
    for (int part = 0; part < 2; ++part) {
      GU t0, t1, t2, t3, t4;
#pragma unroll
      for (int j2 = 0; j2 < 4; ++j2) {
        t0.u[j2] = ga[0][part].u[j2] & gm[0];
        t1.u[j2] = ga[1][part].u[j2] & gm[1];
        t2.u[j2] = ga[2][part].u[j2] & gm[2];
        t3.u[j2] = ga[3][part].u[j2] & gm[3];
        t4.u[j2] = ga[4][part].u[j2] & gm[4];
      }
      half8 s = ((t0.v + t1.v) + (t2.v + t3.v)) + t4.v;
      s = s * den8;
      *(half8*)&s_lds[buf][4096 + (2 * gseg + part) * 512 + grow * 8] = s;
    }
  };
  auto STAGE = [&](int buf, int it) {
    int k0 = it << 6;
    const ushort* ph = h16 + (r0 + lane) * 512 + k0 + 8 * wu;
    const ushort* ps = Ws + (c0 + lane) * 512 + k0 + 8 * wu;
    const ushort* pn = Wn + (c0 + lane) * 512 + k0 + 8 * wu;
    ushort* lb = &s_lds[buf][wu << 9];
#define GLDS(SRC, DST) __builtin_amdgcn_global_load_lds( \
      (const __attribute__((address_space(1))) void*)(SRC), \
      (__attribute__((address_space(3))) void*)(DST), 16, 0, 0)
    GLDS(ph, lb);            GLDS(ph + 32, lb + 2048);
    GLDS(ps, lb + 8192);     GLDS(ps + 32, lb + 10240);
    GLDS(pn, lb + 12288);    GLDS(pn + 32, lb + 14336);
#undef GLDS
  };

  f32x16 accS = {}, accN = {};
  GATHER(0);
  STAGE(0, 0);
  COMBINE(0);
  __syncthreads();
  int cur = 0;
  for (int it = 0; it < 8; ++it) {
    if (it < 7) {
      GATHER(it + 1);
      STAGE(cur ^ 1, it + 1);
    }
    const half8* pAh = (const half8*)&s_lds[cur][0];
    const half8* pAg = (const half8*)&s_lds[cur][4096];
    const half8* pBs = (const half8*)&s_lds[cur][8192];
    const half8* pBn = (const half8*)&s_lds[cur][12288];
#pragma unroll
    for (int ks = 0; ks < 4; ++ks) {
      int gi = (2 * ks + hi) * 64;
      half8 ah = pAh[gi + 32 * wr + lo];
      half8 bs = pBs[gi + 32 * wc + lo];
      accS = __builtin_amdgcn_mfma_f32_32x32x16_f16(ah, bs, accS, 0, 0, 0);
      half8 ag = pAg[gi + 32 * wr + lo];
      half8 bn2 = pBn[gi + 32 * wc + lo];
      accN = __builtin_amdgcn_mfma_f32_32x32x16_f16(ag, bn2, accN, 0, 0, 0);
    }
    if (it < 7) COMBINE(cur ^ 1);
    __syncthreads();
    cur ^= 1;
  }

  const int col = c0 + 32 * wc + lo;
  const float b = bias[col];
#pragma unroll
  for (int r = 0; r < 16; ++r) {
    int row = r0 + 32 * wr + (r & 3) + ((r >> 2) << 3) + (hi << 2);
    float v = fmaxf(accS[r] + accN[r] + b, 0.f);
    if (final_layer) fout[row * 512 + col] = v;
    else hout[row * 512 + col] = __builtin_bit_cast(ushort, (_Float16)v);
  }
}

extern "C" void kernel_launch(void* const* d_in, const int* in_sizes, int n_in,
                              void* d_out, int out_size, void* d_ws, size_t ws_size,
                              hipStream_t stream) {
  const float* imgs   = (const float*)d_in[0];
  const float* pos    = (const float*)d_in[1];
  const float* conv_w = (const float*)d_in[2];
  const float* conv_b = (const float*)d_in[3];
  const float* proj_w = (const float*)d_in[4];
  const float* proj_b = (const float*)d_in[5];
  const float* w_self = (const float*)d_in[6];
  const float* w_nbr  = (const float*)d_in[7];
  const float* b_gnn  = (const float*)d_in[8];

  char* ws = (char*)d_ws;
  ushort* wfrag = (ushort*)(ws);
  float*  enc   = (float*) (ws + 32768);
  ushort* h16a  = (ushort*)(ws + 557056);
  ushort* h16b  = (ushort*)(ws + 2654208);
  ushort* wT16  = (ushort*)(ws + 6848512);
  int*    nbr   = (int*)   (ws + 11042816);
  float*  den   = (float*) (ws + 11083776);

  setup_kernel<<<2604, 256, 0, stream>>>(conv_w, w_self, w_nbr, pos,
                                         wfrag, wT16, nbr, den, enc);
  conv_pool_kernel<<<2 * NNODES, 256, 0, stream>>>(imgs, wfrag, conv_b, enc);
  proj_kernel<<<512, 256, 0, stream>>>(enc, proj_w, proj_b, h16a);

  for (int l = 0; l < 4; ++l) {
    ushort* hin  = (l & 1) ? h16b : h16a;
    ushort* hnew = (l & 1) ? h16a : h16b;
    gnn_gemm_kernel<<<256, 256, 0, stream>>>(
        hin, nbr, den, wT16 + l * 262144, wT16 + (4 + l) * 262144,
        b_gnn + l * 512, hnew, (float*)d_out, (l == 3) ? 1 : 0);
  }
}

// Round 11
// 217.616 us; speedup vs baseline: 1.0057x; 1.0057x over previous
//
#include <hip/hip_runtime.h>

// WinGNN: conv-encode (fp16 MFMA, 1 block/image, 8 waves, B-in-LDS, 2-deep pipe)
// -> radius-KNN -> 4-layer GNN (fp16 MFMA, agg fused into GEMM staging).
//
// Workspace layout (bytes):
//   wfrag @ 0        : 11264 fp16 conv-weight fragments, 22 granules (32768 B slot)
//   enc   @ 32768    : 2048x64 f32 (524288)
//   h16a  @ 557056   : 2048x512 fp16 (2 MB)
//   h16b  @ 2654208  : 2048x512 fp16 (2 MB)
//   wT16  @ 6848512  : 8x512x512 fp16 (4 MB)
//   nbr   @ 11042816 : 2048x5 int (40960 slot)
//   den   @ 11083776 : 2048 f32 (stores 1/count)

#define NNODES 2048

typedef __attribute__((ext_vector_type(8))) _Float16 half8;
typedef __attribute__((ext_vector_type(16))) float f32x16;

__device__ inline uint pack2h(float x, float y) {
  ushort a = __builtin_bit_cast(ushort, (_Float16)x);
  ushort b = __builtin_bit_cast(ushort, (_Float16)y);
  return (uint)a | ((uint)b << 16);
}

// ---------- setup: wfrag prep (44 blocks) | wT prep (512) | knn + enc zero (2048) ----------
__global__ __launch_bounds__(256) void setup_kernel(
    const float* __restrict__ conv_w, const float* __restrict__ wsrc_s,
    const float* __restrict__ wsrc_n, const float* __restrict__ pos,
    ushort* __restrict__ wfrag, ushort* __restrict__ wT,
    int* __restrict__ nbr, float* __restrict__ den, float* __restrict__ enc) {
  __shared__ float4 smem4[1040];        // 16640 B, unioned per role
  const int bid = blockIdx.x;
  const int tid = threadIdx.x;

  if (bid < 44) {
    // conv_w [64][3][7][7] -> B-fragments: (((ct*11+kb)*64+lane)*8+j), 11264 total
    int i = bid * 256 + tid;
    int j = i & 7;
    int l = (i >> 3) & 63;
    int q = i >> 9;            // ct*11 + kb
    int kb = q % 11, ct = q / 11;
    int g = 2 * kb + (l >> 5);
    int c = 32 * ct + (l & 31);
    float val = 0.f;
    if (g < 21 && j < 7) val = conv_w[c * 147 + g * 7 + j];
    wfrag[i] = __builtin_bit_cast(ushort, (_Float16)val);
    return;
  }

  if (bid < 556) {
    // w_self/w_nbr [k][n] f32 -> wT16 [m][n][k] fp16
    float(*s)[65] = (float(*)[65])smem4;
    int bid2 = bid - 44;
    int m = bid2 >> 6, kt = (bid2 >> 3) & 7, nt = bid2 & 7;
    const float* in = (m < 4) ? (wsrc_s + m * 262144) : (wsrc_n + (m - 4) * 262144);
    ushort* out = wT + m * 262144;
    int k0 = kt << 6, n0 = nt << 6;
#pragma unroll
    for (int rep = 0; rep < 4; ++rep) {
      int row = (rep << 4) + (tid >> 4);
      int c4 = (tid & 15) << 2;
      float4 v = *(const float4*)&in[(k0 + row) * 512 + n0 + c4];
      s[row][c4] = v.x; s[row][c4 + 1] = v.y; s[row][c4 + 2] = v.z; s[row][c4 + 3] = v.w;
    }
    __syncthreads();
#pragma unroll
    for (int rep = 0; rep < 4; ++rep) {
      int n = (rep << 4) + (tid >> 4);
      int k4 = (tid & 15) << 2;
      ushort4 o;
      o.x = __builtin_bit_cast(ushort, (_Float16)s[k4 + 0][n]);
      o.y = __builtin_bit_cast(ushort, (_Float16)s[k4 + 1][n]);
      o.z = __builtin_bit_cast(ushort, (_Float16)s[k4 + 2][n]);
      o.w = __builtin_bit_cast(ushort, (_Float16)s[k4 + 3][n]);
      *(ushort4*)&out[(n0 + n) * 512 + k0 + k4] = o;
    }
    return;
  }

  // radius-KNN for node i; also zero enc rows (harmless belt-and-braces)
  {
    float* s_d2 = (float*)smem4;
    int* s_idx = (int*)(s_d2 + NNODES);
    int* s_cnt = (int*)(s_idx + NNODES);
    const int i = bid - 556;
    if (tid < 16) {
      float4 z4 = {0.f, 0.f, 0.f, 0.f};
      ((float4*)(enc + i * 64))[tid] = z4;
    }
    if (tid == 0) *s_cnt = 0;
    __syncthreads();
    const float px = pos[2 * i] * 32.f, py = pos[2 * i + 1] * 32.f;
#pragma unroll
    for (int r = 0; r < 8; ++r) {
      int j = tid + (r << 8);
      float2 q = ((const float2*)pos)[j];
      float dx = q.x * 32.f - px, dy = q.y * 32.f - py;
      float d2 = dx * dx + dy * dy;
      if (d2 <= 2.0f && j != i) {
        int slot = atomicAdd(s_cnt, 1);
        s_d2[slot] = d2;
        s_idx[slot] = j;
      }
    }
    __syncthreads();
    if (tid < 64) {
      const int lane = tid;
      const int cnt = *s_cnt;
      int nf = 0;
#pragma unroll
      for (int k = 0; k < 5; ++k) {
        float best = 1e30f;
        int bslot = 0x7fffffff;
        for (int e = lane; e < cnt; e += 64) {
          float d = s_d2[e];
          if (d < best) { best = d; bslot = e; }
        }
#pragma unroll
        for (int off = 1; off < 64; off <<= 1) {
          float od = __shfl_xor(best, off);
          int os = __shfl_xor(bslot, off);
          if (od < best || (od == best && os < bslot)) { best = od; bslot = os; }
        }
        bool got = (best < 1e30f);
        if (lane == 0) nbr[i * 5 + k] = got ? s_idx[bslot] : -1;
        if (got) { s_d2[bslot] = 1e30f; ++nf; }
      }
      if (lane == 0) den[i] = 1.f / (float)(nf > 0 ? nf : 1);
    }
  }
}

// ---------- conv7x7 s2 SAME + bias + relu + avg pool, fp16 MFMA ----------
// 1 block/image, 512 threads (8 waves); wave w owns out-rows 4w..4w+3
// (2 tp x 2 rows x 2 ch-tiles = 4 MFMA chains, r5-proven 2-deep pipeline).
// LDS: image [3][69][72] fp16 @0 (29808) | wfrag @29808 (22528) | pool @52336 (2048)
// Total 54384 B -> 2 blocks/CU -> 16 waves/CU; regs ~114 incl 64 AGPR -> 4 w/SIMD.
__global__ __launch_bounds__(512, 4) void conv_pool_kernel(
    const float* __restrict__ imgs, const ushort* __restrict__ wfrag,
    const float* __restrict__ cb, float* __restrict__ enc) {
  __shared__ int4 s_all[3399];          // 54384 B
  ushort* s_img = (ushort*)s_all;
  float* s_pool = (float*)((char*)s_all + 52336);

  const int n = blockIdx.x;
  const int tid = threadIdx.x;
  const int lane = tid & 63;
  const int w = tid >> 6;               // 0..7
  const int hi = lane >> 5;
  const int lo = lane & 31;

  // zero image region (1863 int4 = 29808 B)
  int4 z = {0, 0, 0, 0};
  for (int i = tid; i < 1863; i += 512) s_all[i] = z;

  // stage wfrag -> LDS via global_load_lds (1408 int4 = 22528 B)
  {
    char* ldsb = (char*)s_all + 29808;
#pragma unroll
    for (int r = 0; r < 2; ++r) {
      __builtin_amdgcn_global_load_lds(
          (const __attribute__((address_space(1))) void*)(wfrag + (r * 512 + tid) * 8),
          (__attribute__((address_space(3))) void*)(ldsb + (r * 512 + tid) * 16), 16, 0, 0);
    }
    if (tid < 384) {
      __builtin_amdgcn_global_load_lds(
          (const __attribute__((address_space(1))) void*)(wfrag + (1024 + tid) * 8),
          (__attribute__((address_space(3))) void*)(ldsb + (1024 + tid) * 16), 16, 0, 0);
    }
  }
  __syncthreads();   // zeros + wfrag complete

  // stage full image fp32 -> fp16 LDS, padded (+2,+2): 3072 float4
  const float4* src = (const float4*)(imgs + (size_t)n * 12288);
#pragma unroll
  for (int r = 0; r < 6; ++r) {
    int i = r * 512 + tid;
    float4 v = src[i];
    int ic = i >> 10;
    int rem = i & 1023;
    int y = rem >> 4, xq = rem & 15;
    int d = (ic * 69 + y + 2) * 72 + (xq << 2) + 2;   // even
    ((uint*)s_img)[d >> 1] = pack2h(v.x, v.y);
    ((uint*)s_img)[(d >> 1) + 1] = pack2h(v.z, v.w);
  }

  const float bias0 = cb[lo];
  const float bias1 = cb[32 + lo];
  __syncthreads();

  // base addresses (byte offsets into LDS image)
  const char* sb = (const char*)s_img;
  const char* baseA  = sb + 4 * lo + w * 1152 + (hi ? 144 : 0);      // kb != 3
  const char* baseA3 = sb + 4 * lo + w * 1152 + (hi ? 9936 : 864);   // kb == 3 (ic crossing)
  const char* baseB  = (const char*)s_all + 29808 + lane * 16;

  // compile-time A offsets per kb (69-row layout, row(g)= (ic*69+ky)*144):
  // kb:   0    1    2    3      4      5      6      7      8      9     10
  // off:  0  288  576  (A3)  10080  10368  10656  19872  20160  20448  20736

  union F { half8 v; uint u[4]; };
  float poolacc0 = 0.f, poolacc1 = 0.f;

#define LOADA(F0, F1, BASE, OFF, TP) do {                                     \
    const uint* p_ = (const uint*)((BASE) + (OFF) + (TP) * 576);              \
    F0.u[0] = p_[0]; F0.u[1] = p_[1]; F0.u[2] = p_[2]; F0.u[3] = p_[3];       \
    const uint* q_ = (const uint*)((BASE) + (OFF) + (TP) * 576 + 288);        \
    F1.u[0] = q_[0]; F1.u[1] = q_[1]; F1.u[2] = q_[2]; F1.u[3] = q_[3];       \
  } while (0)
#define LOADB(B0, B1, KB) do {                                                \
    B0 = *(const half8*)(baseB + (KB) * 1024);                                \
    B1 = *(const half8*)(baseB + 11264 + (KB) * 1024);                        \
  } while (0)
#define MFMA4(FF0, FF1, BB0, BB1) do {                                        \
    __builtin_amdgcn_s_setprio(1);                                            \
    a0 = __builtin_amdgcn_mfma_f32_32x32x16_f16(FF0.v, BB0, a0, 0, 0, 0);     \
    a1 = __builtin_amdgcn_mfma_f32_32x32x16_f16(FF0.v, BB1, a1, 0, 0, 0);     \
    a2 = __builtin_amdgcn_mfma_f32_32x32x16_f16(FF1.v, BB0, a2, 0, 0, 0);     \
    a3 = __builtin_amdgcn_mfma_f32_32x32x16_f16(FF1.v, BB1, a3, 0, 0, 0);     \
    __builtin_amdgcn_s_setprio(0);                                            \
  } while (0)

#pragma unroll
  for (int tp = 0; tp < 2; ++tp) {
    f32x16 a0 = {}, a1 = {}, a2 = {}, a3 = {};
    F f0a, f1a, f0b, f1b;
    half8 b0a, b1a, b0b, b1b;
    LOADA(f0a, f1a, baseA, 0, tp);        LOADB(b0a, b1a, 0);
    LOADA(f0b, f1b, baseA, 288, tp);      LOADB(b0b, b1b, 1);
    MFMA4(f0a, f1a, b0a, b1a);
    LOADA(f0a, f1a, baseA, 576, tp);      LOADB(b0a, b1a, 2);
    MFMA4(f0b, f1b, b0b, b1b);
    LOADA(f0b, f1b, baseA3, 0, tp);       LOADB(b0b, b1b, 3);
    MFMA4(f0a, f1a, b0a, b1a);
    LOADA(f0a, f1a, baseA, 10080, tp);    LOADB(b0a, b1a, 4);
    MFMA4(f0b, f1b, b0b, b1b);
    LOADA(f0b, f1b, baseA, 10368, tp);    LOADB(b0b, b1b, 5);
    MFMA4(f0a, f1a, b0a, b1a);
    LOADA(f0a, f1a, baseA, 10656, tp);    LOADB(b0a, b1a, 6);
    MFMA4(f0b, f1b, b0b, b1b);
    LOADA(f0b, f1b, baseA, 19872, tp);    LOADB(b0b, b1b, 7);
    MFMA4(f0a, f1a, b0a, b1a);
    LOADA(f0a, f1a, baseA, 20160, tp);    LOADB(b0a, b1a, 8);
    MFMA4(f0b, f1b, b0b, b1b);
    LOADA(f0b, f1b, baseA, 20448, tp);    LOADB(b0b, b1b, 9);
    MFMA4(f0a, f1a, b0a, b1a);
    LOADA(f0a, f1a, baseA, 20736, tp);    LOADB(b0a, b1a, 10);
    MFMA4(f0b, f1b, b0b, b1b);
    MFMA4(f0a, f1a, b0a, b1a);

    float s0 = 0.f, s1 = 0.f;
#pragma unroll
    for (int r = 0; r < 16; ++r) {
      s0 += fmaxf(a0[r] + bias0, 0.f) + fmaxf(a2[r] + bias0, 0.f);
      s1 += fmaxf(a1[r] + bias1, 0.f) + fmaxf(a3[r] + bias1, 0.f);
    }
    poolacc0 += s0;
    poolacc1 += s1;
  }
#undef LOADA
#undef LOADB
#undef MFMA4

  poolacc0 += __shfl_xor(poolacc0, 32);
  poolacc1 += __shfl_xor(poolacc1, 32);
  if (lane < 32) {
    s_pool[w * 64 + lo] = poolacc0;
    s_pool[w * 64 + 32 + lo] = poolacc1;
  }
  __syncthreads();
  if (tid < 64) {
    float s = 0.f;
#pragma unroll
    for (int q = 0; q < 8; ++q) s += s_pool[q * 64 + tid];
    enc[n * 64 + tid] = s * (1.f / 1024.f);   // one block per image: direct store
  }
}

// ---------- proj: relu(enc @ pw + pb) -> h16 [2048][512] fp16 ----------
__global__ __launch_bounds__(256) void proj_kernel(
    const float* __restrict__ enc, const float* __restrict__ pw,
    const float* __restrict__ pb, ushort* __restrict__ h16) {
  int c = ((blockIdx.x & 1) << 8) | threadIdx.x;
  int r0 = (blockIdx.x >> 1) << 3;
  float bias = pb[c];
  float acc[8];
#pragma unroll
  for (int r = 0; r < 8; ++r) acc[r] = bias;
#pragma unroll 4
  for (int k = 0; k < 64; ++k) {
    float w = pw[k * 512 + c];
#pragma unroll
    for (int r = 0; r < 8; ++r) acc[r] = fmaf(enc[(r0 + r) * 64 + k], w, acc[r]);
  }
#pragma unroll
  for (int r = 0; r < 8; ++r)
    h16[(r0 + r) * 512 + c] = __builtin_bit_cast(ushort, (_Float16)fmaxf(acc[r], 0.f));
}

// ---------- GNN layer: out = relu(h@Ws + mean_nbr(h)@Wn + b), agg fused ----------
__global__ __launch_bounds__(256) void gnn_gemm_kernel(
    const ushort* __restrict__ h16, const int* __restrict__ nbr,
    const float* __restrict__ den,
    const ushort* __restrict__ Ws, const ushort* __restrict__ Wn,
    const float* __restrict__ bias, ushort* __restrict__ hout,
    float* __restrict__ fout, int final_layer) {
  __shared__ ushort s_lds[2][16384];
  __shared__ int s_nbr[320];
  __shared__ float s_den[64];
  const int tid = threadIdx.x;
  const int lane = tid & 63;
  const int hi = lane >> 5, lo = lane & 31;
  const int wu = __builtin_amdgcn_readfirstlane(tid >> 6);
  const int wr = wu >> 1, wc = wu & 1;
  const int bm = blockIdx.x >> 3, bn = blockIdx.x & 7;
  const int r0 = bm << 6, c0 = bn << 6;

  if (tid < 80) ((int4*)s_nbr)[tid] = ((const int4*)(nbr + r0 * 5))[tid];
  else if (tid < 96) ((float4*)s_den)[tid - 80] = ((const float4*)(den + r0))[tid - 80];
  __syncthreads();

  const int grow = tid >> 2, gseg = tid & 3;
  int gj[5];
  uint gm[5];
#pragma unroll
  for (int k = 0; k < 5; ++k) {
    int j = s_nbr[grow * 5 + k];
    gm[k] = (j >= 0) ? 0xFFFFFFFFu : 0u;
    gj[k] = (j >= 0) ? j : 0;
  }
  half8 den8;
  {
    _Float16 dh = (_Float16)s_den[grow];
#pragma unroll
    for (int e = 0; e < 8; ++e) den8[e] = dh;
  }

  union GU { half8 v; uint u[4]; };
  GU ga[5][2];

  auto GATHER = [&](int it) {
    const ushort* hb = h16 + (it << 6) + gseg * 16;
#pragma unroll
    for (int k = 0; k < 5; ++k) {
      const half8* p = (const half8*)(hb + gj[k] * 512);
      ga[k][0].v = p[0];
      ga[k][1].v = p[1];
    }
  };
  auto COMBINE = [&](int buf) {
#pragma unroll
    for (int part = 0; part < 2; ++part) {
      GU t0, t1, t2, t3, t4;
#pragma unroll
      for (int j2 = 0; j2 < 4; ++j2) {
        t0.u[j2] = ga[0][part].u[j2] & gm[0];
        t1.u[j2] = ga[1][part].u[j2] & gm[1];
        t2.u[j2] = ga[2][part].u[j2] & gm[2];
        t3.u[j2] = ga[3][part].u[j2] & gm[3];
        t4.u[j2] = ga[4][part].u[j2] & gm[4];
      }
      half8 s = ((t0.v + t1.v) + (t2.v + t3.v)) + t4.v;
      s = s * den8;
      *(half8*)&s_lds[buf][4096 + (2 * gseg + part) * 512 + grow * 8] = s;
    }
  };
  auto STAGE = [&](int buf, int it) {
    int k0 = it << 6;
    const ushort* ph = h16 + (r0 + lane) * 512 + k0 + 8 * wu;
    const ushort* ps = Ws + (c0 + lane) * 512 + k0 + 8 * wu;
    const ushort* pn = Wn + (c0 + lane) * 512 + k0 + 8 * wu;
    ushort* lb = &s_lds[buf][wu << 9];
#define GLDS(SRC, DST) __builtin_amdgcn_global_load_lds( \
      (const __attribute__((address_space(1))) void*)(SRC), \
      (__attribute__((address_space(3))) void*)(DST), 16, 0, 0)
    GLDS(ph, lb);            GLDS(ph + 32, lb + 2048);
    GLDS(ps, lb + 8192);     GLDS(ps + 32, lb + 10240);
    GLDS(pn, lb + 12288);    GLDS(pn + 32, lb + 14336);
#undef GLDS
  };

  f32x16 accS = {}, accN = {};
  GATHER(0);
  STAGE(0, 0);
  COMBINE(0);
  __syncthreads();
  int cur = 0;
  for (int it = 0; it < 8; ++it) {
    if (it < 7) {
      GATHER(it + 1);
      STAGE(cur ^ 1, it + 1);
    }
    const half8* pAh = (const half8*)&s_lds[cur][0];
    const half8* pAg = (const half8*)&s_lds[cur][4096];
    const half8* pBs = (const half8*)&s_lds[cur][8192];
    const half8* pBn = (const half8*)&s_lds[cur][12288];
#pragma unroll
    for (int ks = 0; ks < 4; ++ks) {
      int gi = (2 * ks + hi) * 64;
      half8 ah = pAh[gi + 32 * wr + lo];
      half8 bs = pBs[gi + 32 * wc + lo];
      accS = __builtin_amdgcn_mfma_f32_32x32x16_f16(ah, bs, accS, 0, 0, 0);
      half8 ag = pAg[gi + 32 * wr + lo];
      half8 bn2 = pBn[gi + 32 * wc + lo];
      accN = __builtin_amdgcn_mfma_f32_32x32x16_f16(ag, bn2, accN, 0, 0, 0);
    }
    if (it < 7) COMBINE(cur ^ 1);
    __syncthreads();
    cur ^= 1;
  }

  const int col = c0 + 32 * wc + lo;
  const float b = bias[col];
#pragma unroll
  for (int r = 0; r < 16; ++r) {
    int row = r0 + 32 * wr + (r & 3) + ((r >> 2) << 3) + (hi << 2);
    float v = fmaxf(accS[r] + accN[r] + b, 0.f);
    if (final_layer) fout[row * 512 + col] = v;
    else hout[row * 512 + col] = __builtin_bit_cast(ushort, (_Float16)v);
  }
}

extern "C" void kernel_launch(void* const* d_in, const int* in_sizes, int n_in,
                              void* d_out, int out_size, void* d_ws, size_t ws_size,
                              hipStream_t stream) {
  const float* imgs   = (const float*)d_in[0];
  const float* pos    = (const float*)d_in[1];
  const float* conv_w = (const float*)d_in[2];
  const float* conv_b = (const float*)d_in[3];
  const float* proj_w = (const float*)d_in[4];
  const float* proj_b = (const float*)d_in[5];
  const float* w_self = (const float*)d_in[6];
  const float* w_nbr  = (const float*)d_in[7];
  const float* b_gnn  = (const float*)d_in[8];

  char* ws = (char*)d_ws;
  ushort* wfrag = (ushort*)(ws);
  float*  enc   = (float*) (ws + 32768);
  ushort* h16a  = (ushort*)(ws + 557056);
  ushort* h16b  = (ushort*)(ws + 2654208);
  ushort* wT16  = (ushort*)(ws + 6848512);
  int*    nbr   = (int*)   (ws + 11042816);
  float*  den   = (float*) (ws + 11083776);

  setup_kernel<<<2604, 256, 0, stream>>>(conv_w, w_self, w_nbr, pos,
                                         wfrag, wT16, nbr, den, enc);
  conv_pool_kernel<<<NNODES, 512, 0, stream>>>(imgs, wfrag, conv_b, enc);
  proj_kernel<<<512, 256, 0, stream>>>(enc, proj_w, proj_b, h16a);

  for (int l = 0; l < 4; ++l) {
    ushort* hin  = (l & 1) ? h16b : h16a;
    ushort* hnew = (l & 1) ? h16a : h16b;
    gnn_gemm_kernel<<<256, 256, 0, stream>>>(
        hin, nbr, den, wT16 + l * 262144, wT16 + (4 + l) * 262144,
        b_gnn + l * 512, hnew, (float*)d_out, (l == 3) ? 1 : 0);
  }
}

// Round 12
// 166.748 us; speedup vs baseline: 1.3125x; 1.3051x over previous
//
#include <hip/hip_runtime.h>

// WinGNN: conv-encode (r5-proven fp16 MFMA conv, B-in-LDS, K=176) ->
// radius-KNN -> 4-layer GNN (fp16 MFMA, agg fused into GEMM staging).
//
// Workspace layout (bytes):
//   wfrag @ 0        : 11264 fp16 conv-weight fragments, 22 granules (32768 B slot)
//   enc   @ 32768    : 2048x64 f32 (524288)  [zeroed in setup; conv atomicAdds]
//   h16a  @ 557056   : 2048x512 fp16 (2 MB)
//   h16b  @ 2654208  : 2048x512 fp16 (2 MB)
//   wT16  @ 6848512  : 8x512x512 fp16 (4 MB)
//   nbr   @ 11042816 : 2048x5 int (40960 slot)
//   den   @ 11083776 : 2048 f32 (stores 1/count)

#define NNODES 2048

typedef __attribute__((ext_vector_type(8))) _Float16 half8;
typedef __attribute__((ext_vector_type(16))) float f32x16;

__device__ inline uint pack2h(float x, float y) {
  ushort a = __builtin_bit_cast(ushort, (_Float16)x);
  ushort b = __builtin_bit_cast(ushort, (_Float16)y);
  return (uint)a | ((uint)b << 16);
}

// ---------- setup: wfrag prep (44 blocks) | wT prep (512) | knn + enc zero (2048) ----------
__global__ __launch_bounds__(256) void setup_kernel(
    const float* __restrict__ conv_w, const float* __restrict__ wsrc_s,
    const float* __restrict__ wsrc_n, const float* __restrict__ pos,
    ushort* __restrict__ wfrag, ushort* __restrict__ wT,
    int* __restrict__ nbr, float* __restrict__ den, float* __restrict__ enc) {
  __shared__ float4 smem4[1040];        // 16640 B, unioned per role
  const int bid = blockIdx.x;
  const int tid = threadIdx.x;

  if (bid < 44) {
    // conv_w [64][3][7][7] -> B-fragments: (((ct*11+kb)*64+lane)*8+j), 11264 total
    int i = bid * 256 + tid;
    int j = i & 7;
    int l = (i >> 3) & 63;
    int q = i >> 9;            // ct*11 + kb
    int kb = q % 11, ct = q / 11;
    int g = 2 * kb + (l >> 5);
    int c = 32 * ct + (l & 31);
    float val = 0.f;
    if (g < 21 && j < 7) val = conv_w[c * 147 + g * 7 + j];
    wfrag[i] = __builtin_bit_cast(ushort, (_Float16)val);
    return;
  }

  if (bid < 556) {
    // w_self/w_nbr [k][n] f32 -> wT16 [m][n][k] fp16
    float(*s)[65] = (float(*)[65])smem4;
    int bid2 = bid - 44;
    int m = bid2 >> 6, kt = (bid2 >> 3) & 7, nt = bid2 & 7;
    const float* in = (m < 4) ? (wsrc_s + m * 262144) : (wsrc_n + (m - 4) * 262144);
    ushort* out = wT + m * 262144;
    int k0 = kt << 6, n0 = nt << 6;
#pragma unroll
    for (int rep = 0; rep < 4; ++rep) {
      int row = (rep << 4) + (tid >> 4);
      int c4 = (tid & 15) << 2;
      float4 v = *(const float4*)&in[(k0 + row) * 512 + n0 + c4];
      s[row][c4] = v.x; s[row][c4 + 1] = v.y; s[row][c4 + 2] = v.z; s[row][c4 + 3] = v.w;
    }
    __syncthreads();
#pragma unroll
    for (int rep = 0; rep < 4; ++rep) {
      int n = (rep << 4) + (tid >> 4);
      int k4 = (tid & 15) << 2;
      ushort4 o;
      o.x = __builtin_bit_cast(ushort, (_Float16)s[k4 + 0][n]);
      o.y = __builtin_bit_cast(ushort, (_Float16)s[k4 + 1][n]);
      o.z = __builtin_bit_cast(ushort, (_Float16)s[k4 + 2][n]);
      o.w = __builtin_bit_cast(ushort, (_Float16)s[k4 + 3][n]);
      *(ushort4*)&out[(n0 + n) * 512 + k0 + k4] = o;
    }
    return;
  }

  // radius-KNN for node i; also zero enc rows for conv's atomicAdd
  {
    float* s_d2 = (float*)smem4;
    int* s_idx = (int*)(s_d2 + NNODES);
    int* s_cnt = (int*)(s_idx + NNODES);
    const int i = bid - 556;
    if (tid < 16) {
      float4 z4 = {0.f, 0.f, 0.f, 0.f};
      ((float4*)(enc + i * 64))[tid] = z4;
    }
    if (tid == 0) *s_cnt = 0;
    __syncthreads();
    const float px = pos[2 * i] * 32.f, py = pos[2 * i + 1] * 32.f;
#pragma unroll
    for (int r = 0; r < 8; ++r) {
      int j = tid + (r << 8);
      float2 q = ((const float2*)pos)[j];
      float dx = q.x * 32.f - px, dy = q.y * 32.f - py;
      float d2 = dx * dx + dy * dy;
      if (d2 <= 2.0f && j != i) {
        int slot = atomicAdd(s_cnt, 1);
        s_d2[slot] = d2;
        s_idx[slot] = j;
      }
    }
    __syncthreads();
    if (tid < 64) {
      const int lane = tid;
      const int cnt = *s_cnt;
      int nf = 0;
#pragma unroll
      for (int k = 0; k < 5; ++k) {
        float best = 1e30f;
        int bslot = 0x7fffffff;
        for (int e = lane; e < cnt; e += 64) {
          float d = s_d2[e];
          if (d < best) { best = d; bslot = e; }
        }
#pragma unroll
        for (int off = 1; off < 64; off <<= 1) {
          float od = __shfl_xor(best, off);
          int os = __shfl_xor(bslot, off);
          if (od < best || (od == best && os < bslot)) { best = od; bslot = os; }
        }
        bool got = (best < 1e30f);
        if (lane == 0) nbr[i * 5 + k] = got ? s_idx[bslot] : -1;
        if (got) { s_d2[bslot] = 1e30f; ++nf; }
      }
      if (lane == 0) den[i] = 1.f / (float)(nf > 0 ? nf : 1);
    }
  }
}

// ---------- conv7x7 s2 SAME + bias + relu + avg pool, fp16 MFMA ----------
// r5-proven structure: 2 blocks/image (16 out rows), 4 waves, wave = 2 rows x
// 2 ch-tiles per tp (4 MFMA chains), B-in-LDS, 2-deep register pipeline.
// K trimmed 192->176 (11 granules; kb=10/hi=1 is the only zero-B pad).
// LDS: image [3][37][72] fp16 @0 (15984) | wfrag @15984 (22528) | pool @38512 (1024)
__global__ __launch_bounds__(256, 3) void conv_pool_kernel(
    const float* __restrict__ imgs, const ushort* __restrict__ wfrag,
    const float* __restrict__ cb, float* __restrict__ enc) {
  __shared__ int4 s_all[2471];          // 39536 B
  ushort* s_img = (ushort*)s_all;
  const half8* swf8 = (const half8*)((char*)s_all + 15984);
  float* s_pool = (float*)((char*)s_all + 38512);

  const int n = blockIdx.x >> 1;
  const int r0half = blockIdx.x & 1;    // 0: out rows 0-15, 1: rows 16-31
  const int wy = 32 * r0half - 2;       // input window start row
  const int tid = threadIdx.x;
  const int lane = tid & 63;
  const int w = tid >> 6;
  const int hi = lane >> 5;
  const int lo = lane & 31;

  // zero image region (999 int4 = 15984 B)
  int4 z = {0, 0, 0, 0};
  for (int i = tid; i < 999; i += 256) s_all[i] = z;
  __syncthreads();

  // stage wfrag -> LDS (1408 int4 = 22528 B)
  {
    const int4* wf4 = (const int4*)wfrag;
    int4* swf4 = (int4*)((char*)s_all + 15984);
    for (int i = tid; i < 1408; i += 256) swf4[i] = wf4[i];
  }

  // stage image window fp32 -> fp16 LDS (3 ic x 37 rows x 16 float4)
  const float4* src = (const float4*)(imgs + (size_t)n * 12288);
  for (int i = tid; i < 1776; i += 256) {
    int ic = i / 592;
    int rem = i - ic * 592;
    int li = rem >> 4, xq = rem & 15;
    int iy = wy + li;
    if (iy >= 0 && iy < 64) {
      float4 v = src[(ic * 64 + iy) * 16 + xq];
      int d = (ic * 37 + li) * 72 + (xq << 2) + 2;
      ((uint*)s_img)[d >> 1] = pack2h(v.x, v.y);
      ((uint*)s_img)[(d >> 1) + 1] = pack2h(v.z, v.w);
    }
  }

  // per-lane A base offsets; wave row base baked in
  int aoff[11];
#pragma unroll
  for (int kb = 0; kb < 11; ++kb) {
    int g = 2 * kb + hi;
    if (g > 20) g = 20;               // only (kb=10,hi=1): B-frag is zero
    int ic = g / 7, ky = g - ic * 7;
    aoff[kb] = (ic * 37 + ky) * 144 + 4 * lo + w * 1152;
  }
  const float bias0 = cb[lo];
  const float bias1 = cb[32 + lo];
  float pool0 = 0.f, pool1 = 0.f;
  __syncthreads();

  const char* sb = (const char*)s_img;
  union F { half8 v; uint u[4]; };

#define LOADF(F0, F1, B0, B1, KB, TPADD) do {                       \
    const char* p_ = sb + aoff[KB] + (TPADD);                       \
    F0.u[0] = *(const uint*)(p_);       F0.u[1] = *(const uint*)(p_ + 4);   \
    F0.u[2] = *(const uint*)(p_ + 8);   F0.u[3] = *(const uint*)(p_ + 12);  \
    F1.u[0] = *(const uint*)(p_ + 288); F1.u[1] = *(const uint*)(p_ + 292); \
    F1.u[2] = *(const uint*)(p_ + 296); F1.u[3] = *(const uint*)(p_ + 300); \
    B0 = swf8[(KB) * 64 + lane];        B1 = swf8[(11 + (KB)) * 64 + lane]; \
  } while (0)
#define MFMA4(FF0, FF1, BB0, BB1) do {                                      \
    a0 = __builtin_amdgcn_mfma_f32_32x32x16_f16(FF0.v, BB0, a0, 0, 0, 0);   \
    a1 = __builtin_amdgcn_mfma_f32_32x32x16_f16(FF0.v, BB1, a1, 0, 0, 0);   \
    a2 = __builtin_amdgcn_mfma_f32_32x32x16_f16(FF1.v, BB0, a2, 0, 0, 0);   \
    a3 = __builtin_amdgcn_mfma_f32_32x32x16_f16(FF1.v, BB1, a3, 0, 0, 0);   \
  } while (0)

#pragma unroll
  for (int tp = 0; tp < 2; ++tp) {
    const int tpadd = tp * 576;
    f32x16 a0 = {}, a1 = {}, a2 = {}, a3 = {};
    F f0a, f1a, f0b, f1b;
    half8 b0a, b1a, b0b, b1b;
    LOADF(f0a, f1a, b0a, b1a, 0, tpadd);
#pragma unroll
    for (int kb = 0; kb < 10; kb += 2) {
      LOADF(f0b, f1b, b0b, b1b, kb + 1, tpadd);
      MFMA4(f0a, f1a, b0a, b1a);
      LOADF(f0a, f1a, b0a, b1a, kb + 2, tpadd);
      MFMA4(f0b, f1b, b0b, b1b);
    }
    MFMA4(f0a, f1a, b0a, b1a);         // kb = 10
    float s0 = 0.f, s1 = 0.f;
#pragma unroll
    for (int r = 0; r < 16; ++r) {
      s0 += fmaxf(a0[r] + bias0, 0.f) + fmaxf(a2[r] + bias0, 0.f);
      s1 += fmaxf(a1[r] + bias1, 0.f) + fmaxf(a3[r] + bias1, 0.f);
    }
    pool0 += s0;
    pool1 += s1;
  }
#undef LOADF
#undef MFMA4

  pool0 += __shfl_xor(pool0, 32);
  pool1 += __shfl_xor(pool1, 32);
  if (lane < 32) {
    s_pool[w * 64 + lo] = pool0;
    s_pool[w * 64 + 32 + lo] = pool1;
  }
  __syncthreads();
  if (tid < 64) {
    float s = s_pool[tid] + s_pool[64 + tid] + s_pool[128 + tid] + s_pool[192 + tid];
    atomicAdd(&enc[n * 64 + tid], s * (1.f / 1024.f));   // 2 addends: commutative
  }
}

// ---------- proj: relu(enc @ pw + pb) -> h16 [2048][512] fp16 ----------
__global__ __launch_bounds__(256) void proj_kernel(
    const float* __restrict__ enc, const float* __restrict__ pw,
    const float* __restrict__ pb, ushort* __restrict__ h16) {
  int c = ((blockIdx.x & 1) << 8) | threadIdx.x;
  int r0 = (blockIdx.x >> 1) << 3;
  float bias = pb[c];
  float acc[8];
#pragma unroll
  for (int r = 0; r < 8; ++r) acc[r] = bias;
#pragma unroll 4
  for (int k = 0; k < 64; ++k) {
    float w = pw[k * 512 + c];
#pragma unroll
    for (int r = 0; r < 8; ++r) acc[r] = fmaf(enc[(r0 + r) * 64 + k], w, acc[r]);
  }
#pragma unroll
  for (int r = 0; r < 8; ++r)
    h16[(r0 + r) * 512 + c] = __builtin_bit_cast(ushort, (_Float16)fmaxf(acc[r], 0.f));
}

// ---------- GNN layer: out = relu(h@Ws + mean_nbr(h)@Wn + b), agg fused ----------
__global__ __launch_bounds__(256) void gnn_gemm_kernel(
    const ushort* __restrict__ h16, const int* __restrict__ nbr,
    const float* __restrict__ den,
    const ushort* __restrict__ Ws, const ushort* __restrict__ Wn,
    const float* __restrict__ bias, ushort* __restrict__ hout,
    float* __restrict__ fout, int final_layer) {
  __shared__ ushort s_lds[2][16384];
  __shared__ int s_nbr[320];
  __shared__ float s_den[64];
  const int tid = threadIdx.x;
  const int lane = tid & 63;
  const int hi = lane >> 5, lo = lane & 31;
  const int wu = __builtin_amdgcn_readfirstlane(tid >> 6);
  const int wr = wu >> 1, wc = wu & 1;
  const int bm = blockIdx.x >> 3, bn = blockIdx.x & 7;
  const int r0 = bm << 6, c0 = bn << 6;

  if (tid < 80) ((int4*)s_nbr)[tid] = ((const int4*)(nbr + r0 * 5))[tid];
  else if (tid < 96) ((float4*)s_den)[tid - 80] = ((const float4*)(den + r0))[tid - 80];
  __syncthreads();

  const int grow = tid >> 2, gseg = tid & 3;
  int gj[5];
  uint gm[5];
#pragma unroll
  for (int k = 0; k < 5; ++k) {
    int j = s_nbr[grow * 5 + k];
    gm[k] = (j >= 0) ? 0xFFFFFFFFu : 0u;
    gj[k] = (j >= 0) ? j : 0;
  }
  half8 den8;
  {
    _Float16 dh = (_Float16)s_den[grow];
#pragma unroll
    for (int e = 0; e < 8; ++e) den8[e] = dh;
  }

  union GU { half8 v; uint u[4]; };
  GU ga[5][2];

  auto GATHER = [&](int it) {
    const ushort* hb = h16 + (it << 6) + gseg * 16;
#pragma unroll
    for (int k = 0; k < 5; ++k) {
      const half8* p = (const half8*)(hb + gj[k] * 512);
      ga[k][0].v = p[0];
      ga[k][1].v = p[1];
    }
  };
  auto COMBINE = [&](int buf) {
#pragma unroll
    for (int part = 0; part < 2; ++part) {
      GU t0, t1, t2, t3, t4;
#pragma unroll
      for (int j2 = 0; j2 < 4; ++j2) {
        t0.u[j2] = ga[0][part].u[j2] & gm[0];
        t1.u[j2] = ga[1][part].u[j2] & gm[1];
        t2.u[j2] = ga[2][part].u[j2] & gm[2];
        t3.u[j2] = ga[3][part].u[j2] & gm[3];
        t4.u[j2] = ga[4][part].u[j2] & gm[4];
      }
      half8 s = ((t0.v + t1.v) + (t2.v + t3.v)) + t4.v;
      s = s * den8;
      *(half8*)&s_lds[buf][4096 + (2 * gseg + part) * 512 + grow * 8] = s;
    }
  };
  auto STAGE = [&](int buf, int it) {
    int k0 = it << 6;
    const ushort* ph = h16 + (r0 + lane) * 512 + k0 + 8 * wu;
    const ushort* ps = Ws + (c0 + lane) * 512 + k0 + 8 * wu;
    const ushort* pn = Wn + (c0 + lane) * 512 + k0 + 8 * wu;
    ushort* lb = &s_lds[buf][wu << 9];
#define GLDS(SRC, DST) __builtin_amdgcn_global_load_lds( \
      (const __attribute__((address_space(1))) void*)(SRC), \
      (__attribute__((address_space(3))) void*)(DST), 16, 0, 0)
    GLDS(ph, lb);            GLDS(ph + 32, lb + 2048);
    GLDS(ps, lb + 8192);     GLDS(ps + 32, lb + 10240);
    GLDS(pn, lb + 12288);    GLDS(pn + 32, lb + 14336);
#undef GLDS
  };

  f32x16 accS = {}, accN = {};
  GATHER(0);
  STAGE(0, 0);
  COMBINE(0);
  __syncthreads();
  int cur = 0;
  for (int it = 0; it < 8; ++it) {
    if (it < 7) {
      GATHER(it + 1);
      STAGE(cur ^ 1, it + 1);
    }
    const half8* pAh = (const half8*)&s_lds[cur][0];
    const half8* pAg = (const half8*)&s_lds[cur][4096];
    const half8* pBs = (const half8*)&s_lds[cur][8192];
    const half8* pBn = (const half8*)&s_lds[cur][12288];
#pragma unroll
    for (int ks = 0; ks < 4; ++ks) {
      int gi = (2 * ks + hi) * 64;
      half8 ah = pAh[gi + 32 * wr + lo];
      half8 bs = pBs[gi + 32 * wc + lo];
      accS = __builtin_amdgcn_mfma_f32_32x32x16_f16(ah, bs, accS, 0, 0, 0);
      half8 ag = pAg[gi + 32 * wr + lo];
      half8 bn2 = pBn[gi + 32 * wc + lo];
      accN = __builtin_amdgcn_mfma_f32_32x32x16_f16(ag, bn2, accN, 0, 0, 0);
    }
    if (it < 7) COMBINE(cur ^ 1);
    __syncthreads();
    cur ^= 1;
  }

  const int col = c0 + 32 * wc + lo;
  const float b = bias[col];
#pragma unroll
  for (int r = 0; r < 16; ++r) {
    int row = r0 + 32 * wr + (r & 3) + ((r >> 2) << 3) + (hi << 2);
    float v = fmaxf(accS[r] + accN[r] + b, 0.f);
    if (final_layer) fout[row * 512 + col] = v;
    else hout[row * 512 + col] = __builtin_bit_cast(ushort, (_Float16)v);
  }
}

extern "C" void kernel_launch(void* const* d_in, const int* in_sizes, int n_in,
                              void* d_out, int out_size, void* d_ws, size_t ws_size,
                              hipStream_t stream) {
  const float* imgs   = (const float*)d_in[0];
  const float* pos    = (const float*)d_in[1];
  const float* conv_w = (const float*)d_in[2];
  const float* conv_b = (const float*)d_in[3];
  const float* proj_w = (const float*)d_in[4];
  const float* proj_b = (const float*)d_in[5];
  const float* w_self = (const float*)d_in[6];
  const float* w_nbr  = (const float*)d_in[7];
  const float* b_gnn  = (const float*)d_in[8];

  char* ws = (char*)d_ws;
  ushort* wfrag = (ushort*)(ws);
  float*  enc   = (float*) (ws + 32768);
  ushort* h16a  = (ushort*)(ws + 557056);
  ushort* h16b  = (ushort*)(ws + 2654208);
  ushort* wT16  = (ushort*)(ws + 6848512);
  int*    nbr   = (int*)   (ws + 11042816);
  float*  den   = (float*) (ws + 11083776);

  setup_kernel<<<2604, 256, 0, stream>>>(conv_w, w_self, w_nbr, pos,
                                         wfrag, wT16, nbr, den, enc);
  conv_pool_kernel<<<2 * NNODES, 256, 0, stream>>>(imgs, wfrag, conv_b, enc);
  proj_kernel<<<512, 256, 0, stream>>>(enc, proj_w, proj_b, h16a);

  for (int l = 0; l < 4; ++l) {
    ushort* hin  = (l & 1) ? h16b : h16a;
    ushort* hnew = (l & 1) ? h16a : h16b;
    gnn_gemm_kernel<<<256, 256, 0, stream>>>(
        hin, nbr, den, wT16 + l * 262144, wT16 + (4 + l) * 262144,
        b_gnn + l * 512, hnew, (float*)d_out, (l == 3) ? 1 : 0);
  }
}

// Round 13
// 141.728 us; speedup vs baseline: 1.5442x; 1.1765x over previous
//
#include <hip/hip_runtime.h>

// WinGNN: conv-encode (r5-verbatim fp16 MFMA conv, B-in-LDS, K=192) ->
// radius-KNN -> 4-layer GNN (fp16 MFMA, agg fused into GEMM staging).
//
// Workspace layout (bytes):
//   wfrag @ 0        : 12288 fp16 conv-weight fragments, 24 granules (32768 B slot)
//   enc   @ 32768    : 2048x64 f32 (524288)  [zeroed in setup; conv atomicAdds]
//   h16a  @ 557056   : 2048x512 fp16 (2 MB)
//   h16b  @ 2654208  : 2048x512 fp16 (2 MB)
//   wT16  @ 6848512  : 8x512x512 fp16 (4 MB)
//   nbr   @ 11042816 : 2048x5 int (40960 slot)
//   den   @ 11083776 : 2048 f32 (stores 1/count)

#define NNODES 2048

typedef __attribute__((ext_vector_type(8))) _Float16 half8;
typedef __attribute__((ext_vector_type(16))) float f32x16;

__device__ inline uint pack2h(float x, float y) {
  ushort a = __builtin_bit_cast(ushort, (_Float16)x);
  ushort b = __builtin_bit_cast(ushort, (_Float16)y);
  return (uint)a | ((uint)b << 16);
}

// ---------- setup: wfrag prep (48 blocks) | wT prep (512) | knn + enc zero (2048) ----------
__global__ __launch_bounds__(256) void setup_kernel(
    const float* __restrict__ conv_w, const float* __restrict__ wsrc_s,
    const float* __restrict__ wsrc_n, const float* __restrict__ pos,
    ushort* __restrict__ wfrag, ushort* __restrict__ wT,
    int* __restrict__ nbr, float* __restrict__ den, float* __restrict__ enc) {
  __shared__ float4 smem4[1040];        // 16640 B, unioned per role
  const int bid = blockIdx.x;
  const int tid = threadIdx.x;

  if (bid < 48) {
    // conv_w [64][3][7][7] -> B-fragments: (((ct*12+kb)*64+lane)*8+j), 12288 total
    int i = bid * 256 + tid;
    int j = i & 7;
    int l = (i >> 3) & 63;
    int q = i >> 9;            // ct*12 + kb
    int kb = q % 12, ct = q / 12;
    int g = 2 * kb + (l >> 5);
    int c = 32 * ct + (l & 31);
    float val = 0.f;
    if (g < 21 && j < 7) val = conv_w[c * 147 + g * 7 + j];
    wfrag[i] = __builtin_bit_cast(ushort, (_Float16)val);
    return;
  }

  if (bid < 560) {
    // w_self/w_nbr [k][n] f32 -> wT16 [m][n][k] fp16
    float(*s)[65] = (float(*)[65])smem4;
    int bid2 = bid - 48;
    int m = bid2 >> 6, kt = (bid2 >> 3) & 7, nt = bid2 & 7;
    const float* in = (m < 4) ? (wsrc_s + m * 262144) : (wsrc_n + (m - 4) * 262144);
    ushort* out = wT + m * 262144;
    int k0 = kt << 6, n0 = nt << 6;
#pragma unroll
    for (int rep = 0; rep < 4; ++rep) {
      int row = (rep << 4) + (tid >> 4);
      int c4 = (tid & 15) << 2;
      float4 v = *(const float4*)&in[(k0 + row) * 512 + n0 + c4];
      s[row][c4] = v.x; s[row][c4 + 1] = v.y; s[row][c4 + 2] = v.z; s[row][c4 + 3] = v.w;
    }
    __syncthreads();
#pragma unroll
    for (int rep = 0; rep < 4; ++rep) {
      int n = (rep << 4) + (tid >> 4);
      int k4 = (tid & 15) << 2;
      ushort4 o;
      o.x = __builtin_bit_cast(ushort, (_Float16)s[k4 + 0][n]);
      o.y = __builtin_bit_cast(ushort, (_Float16)s[k4 + 1][n]);
      o.z = __builtin_bit_cast(ushort, (_Float16)s[k4 + 2][n]);
      o.w = __builtin_bit_cast(ushort, (_Float16)s[k4 + 3][n]);
      *(ushort4*)&out[(n0 + n) * 512 + k0 + k4] = o;
    }
    return;
  }

  // radius-KNN for node i; also zero enc rows for conv's atomicAdd
  {
    float* s_d2 = (float*)smem4;
    int* s_idx = (int*)(s_d2 + NNODES);
    int* s_cnt = (int*)(s_idx + NNODES);
    const int i = bid - 560;
    if (tid < 16) {
      float4 z4 = {0.f, 0.f, 0.f, 0.f};
      ((float4*)(enc + i * 64))[tid] = z4;
    }
    if (tid == 0) *s_cnt = 0;
    __syncthreads();
    const float px = pos[2 * i] * 32.f, py = pos[2 * i + 1] * 32.f;
#pragma unroll
    for (int r = 0; r < 8; ++r) {
      int j = tid + (r << 8);
      float2 q = ((const float2*)pos)[j];
      float dx = q.x * 32.f - px, dy = q.y * 32.f - py;
      float d2 = dx * dx + dy * dy;
      if (d2 <= 2.0f && j != i) {
        int slot = atomicAdd(s_cnt, 1);
        s_d2[slot] = d2;
        s_idx[slot] = j;
      }
    }
    __syncthreads();
    if (tid < 64) {
      const int lane = tid;
      const int cnt = *s_cnt;
      int nf = 0;
#pragma unroll
      for (int k = 0; k < 5; ++k) {
        float best = 1e30f;
        int bslot = 0x7fffffff;
        for (int e = lane; e < cnt; e += 64) {
          float d = s_d2[e];
          if (d < best) { best = d; bslot = e; }
        }
#pragma unroll
        for (int off = 1; off < 64; off <<= 1) {
          float od = __shfl_xor(best, off);
          int os = __shfl_xor(bslot, off);
          if (od < best || (od == best && os < bslot)) { best = od; bslot = os; }
        }
        bool got = (best < 1e30f);
        if (lane == 0) nbr[i * 5 + k] = got ? s_idx[bslot] : -1;
        if (got) { s_d2[bslot] = 1e30f; ++nf; }
      }
      if (lane == 0) den[i] = 1.f / (float)(nf > 0 ? nf : 1);
    }
  }
}

// ---------- conv7x7 s2 SAME + bias + relu + avg pool, fp16 MFMA ----------
// r5-verbatim: 2 blocks/image (16 output rows each), 4 waves/block.
// B-fragments in LDS; explicit 2-deep register pipeline; K=192 (12 granules).
// LDS: image [3][37][72] fp16 @0 (15984 B) | wfrag @15984 (24576 B) | pool @40560 (1024 B)
__global__ __launch_bounds__(256, 3) void conv_pool_kernel(
    const float* __restrict__ imgs, const ushort* __restrict__ wfrag,
    const float* __restrict__ cb, float* __restrict__ enc) {
  __shared__ int4 s_all[2599];          // 41584 B
  ushort* s_img = (ushort*)s_all;
  const half8* swf8 = (const half8*)((char*)s_all + 15984);
  float* s_pool = (float*)((char*)s_all + 40560);

  const int n = blockIdx.x >> 1;
  const int r0half = blockIdx.x & 1;    // 0: rows 0-15, 1: rows 16-31
  const int wy = 32 * r0half - 2;       // input window start row
  const int tid = threadIdx.x;
  const int lane = tid & 63;
  const int w = tid >> 6;
  const int hi = lane >> 5;
  const int lo = lane & 31;

  // zero image region (999 int4 = 15984 B)
  int4 z = {0, 0, 0, 0};
  for (int i = tid; i < 999; i += 256) s_all[i] = z;
  __syncthreads();

  // stage wfrag -> LDS (1536 int4)
  const int4* wf4 = (const int4*)wfrag;
  int4* swf4 = (int4*)((char*)s_all + 15984);
#pragma unroll
  for (int r = 0; r < 6; ++r) swf4[tid + r * 256] = wf4[tid + r * 256];

  // stage image window fp32 -> fp16 (3 ic x 37 rows x 16 float4)
  const float4* src = (const float4*)(imgs + (size_t)n * 12288);
  for (int i = tid; i < 1776; i += 256) {
    int ic = i / 592;
    int rem = i - ic * 592;
    int li = rem >> 4, xq = rem & 15;
    int iy = wy + li;
    if (iy >= 0 && iy < 64) {
      float4 v = src[(ic * 64 + iy) * 16 + xq];
      int d = (ic * 37 + li) * 72 + (xq << 2) + 2;   // element index, d%4==2
      ((uint*)s_img)[d >> 1] = pack2h(v.x, v.y);
      ((uint*)s_img)[(d >> 1) + 1] = pack2h(v.z, v.w);
    }
  }

  // per-lane A-fragment base offsets (row-local base for this wave baked in)
  int aoff[12];
#pragma unroll
  for (int kb = 0; kb < 12; ++kb) {
    int g = 2 * kb + hi;
    if (g > 20) g = 20;               // padding group: B-frag is zero
    int ic = g / 7, ky = g - ic * 7;
    aoff[kb] = (ic * 37 + ky) * 144 + 4 * lo + w * 1152;
  }
  const float bias0 = cb[lo];
  const float bias1 = cb[32 + lo];
  float pool0 = 0.f, pool1 = 0.f;
  __syncthreads();

  const char* sb = (const char*)s_img;
  union F { half8 v; uint u[4]; };

#define LOADF(F0, F1, B0, B1, KB, TPADD) do {                       \
    const char* p_ = sb + aoff[KB] + (TPADD);                       \
    F0.u[0] = *(const uint*)(p_);       F0.u[1] = *(const uint*)(p_ + 4);   \
    F0.u[2] = *(const uint*)(p_ + 8);   F0.u[3] = *(const uint*)(p_ + 12);  \
    F1.u[0] = *(const uint*)(p_ + 288); F1.u[1] = *(const uint*)(p_ + 292); \
    F1.u[2] = *(const uint*)(p_ + 296); F1.u[3] = *(const uint*)(p_ + 300); \
    B0 = swf8[(KB) * 64 + lane];        B1 = swf8[(12 + (KB)) * 64 + lane]; \
  } while (0)

#pragma unroll
  for (int tp = 0; tp < 2; ++tp) {
    const int tpadd = tp * 576;
    f32x16 a0 = {}, a1 = {}, a2 = {}, a3 = {};
    F f0a, f1a, f0b, f1b;
    half8 b0a, b1a, b0b, b1b;
    LOADF(f0a, f1a, b0a, b1a, 0, tpadd);
#pragma unroll
    for (int kb = 0; kb < 12; kb += 2) {
      LOADF(f0b, f1b, b0b, b1b, kb + 1, tpadd);
      a0 = __builtin_amdgcn_mfma_f32_32x32x16_f16(f0a.v, b0a, a0, 0, 0, 0);
      a1 = __builtin_amdgcn_mfma_f32_32x32x16_f16(f0a.v, b1a, a1, 0, 0, 0);
      a2 = __builtin_amdgcn_mfma_f32_32x32x16_f16(f1a.v, b0a, a2, 0, 0, 0);
      a3 = __builtin_amdgcn_mfma_f32_32x32x16_f16(f1a.v, b1a, a3, 0, 0, 0);
      if (kb + 2 < 12) LOADF(f0a, f1a, b0a, b1a, kb + 2, tpadd);
      a0 = __builtin_amdgcn_mfma_f32_32x32x16_f16(f0b.v, b0b, a0, 0, 0, 0);
      a1 = __builtin_amdgcn_mfma_f32_32x32x16_f16(f0b.v, b1b, a1, 0, 0, 0);
      a2 = __builtin_amdgcn_mfma_f32_32x32x16_f16(f1b.v, b0b, a2, 0, 0, 0);
      a3 = __builtin_amdgcn_mfma_f32_32x32x16_f16(f1b.v, b1b, a3, 0, 0, 0);
    }
    float s0 = 0.f, s1 = 0.f;
#pragma unroll
    for (int r = 0; r < 16; ++r) {
      s0 += fmaxf(a0[r] + bias0, 0.f) + fmaxf(a2[r] + bias0, 0.f);
      s1 += fmaxf(a1[r] + bias1, 0.f) + fmaxf(a3[r] + bias1, 0.f);
    }
    pool0 += s0;
    pool1 += s1;
  }
#undef LOADF

  pool0 += __shfl_xor(pool0, 32);
  pool1 += __shfl_xor(pool1, 32);
  if (lane < 32) {
    s_pool[w * 64 + lo] = pool0;
    s_pool[w * 64 + 32 + lo] = pool1;
  }
  __syncthreads();
  if (tid < 64) {
    float s = s_pool[tid] + s_pool[64 + tid] + s_pool[128 + tid] + s_pool[192 + tid];
    atomicAdd(&enc[n * 64 + tid], s * (1.f / 1024.f));   // 2 addends: order-invariant
  }
}

// ---------- proj: relu(enc @ pw + pb) -> h16 [2048][512] fp16 ----------
__global__ __launch_bounds__(256) void proj_kernel(
    const float* __restrict__ enc, const float* __restrict__ pw,
    const float* __restrict__ pb, ushort* __restrict__ h16) {
  int c = ((blockIdx.x & 1) << 8) | threadIdx.x;
  int r0 = (blockIdx.x >> 1) << 3;
  float bias = pb[c];
  float acc[8];
#pragma unroll
  for (int r = 0; r < 8; ++r) acc[r] = bias;
#pragma unroll 4
  for (int k = 0; k < 64; ++k) {
    float w = pw[k * 512 + c];
#pragma unroll
    for (int r = 0; r < 8; ++r) acc[r] = fmaf(enc[(r0 + r) * 64 + k], w, acc[r]);
  }
#pragma unroll
  for (int r = 0; r < 8; ++r)
    h16[(r0 + r) * 512 + c] = __builtin_bit_cast(ushort, (_Float16)fmaxf(acc[r], 0.f));
}

// ---------- GNN layer: out = relu(h@Ws + mean_nbr(h)@Wn + b), agg fused ----------
__global__ __launch_bounds__(256) void gnn_gemm_kernel(
    const ushort* __restrict__ h16, const int* __restrict__ nbr,
    const float* __restrict__ den,
    const ushort* __restrict__ Ws, const ushort* __restrict__ Wn,
    const float* __restrict__ bias, ushort* __restrict__ hout,
    float* __restrict__ fout, int final_layer) {
  __shared__ ushort s_lds[2][16384];
  __shared__ int s_nbr[320];
  __shared__ float s_den[64];
  const int tid = threadIdx.x;
  const int lane = tid & 63;
  const int hi = lane >> 5, lo = lane & 31;
  const int wu = __builtin_amdgcn_readfirstlane(tid >> 6);
  const int wr = wu >> 1, wc = wu & 1;
  const int bm = blockIdx.x >> 3, bn = blockIdx.x & 7;
  const int r0 = bm << 6, c0 = bn << 6;

  if (tid < 80) ((int4*)s_nbr)[tid] = ((const int4*)(nbr + r0 * 5))[tid];
  else if (tid < 96) ((float4*)s_den)[tid - 80] = ((const float4*)(den + r0))[tid - 80];
  __syncthreads();

  const int grow = tid >> 2, gseg = tid & 3;
  int gj[5];
  uint gm[5];
#pragma unroll
  for (int k = 0; k < 5; ++k) {
    int j = s_nbr[grow * 5 + k];
    gm[k] = (j >= 0) ? 0xFFFFFFFFu : 0u;
    gj[k] = (j >= 0) ? j : 0;
  }
  half8 den8;
  {
    _Float16 dh = (_Float16)s_den[grow];
#pragma unroll
    for (int e = 0; e < 8; ++e) den8[e] = dh;
  }

  union GU { half8 v; uint u[4]; };
  GU ga[5][2];

  auto GATHER = [&](int it) {
    const ushort* hb = h16 + (it << 6) + gseg * 16;
#pragma unroll
    for (int k = 0; k < 5; ++k) {
      const half8* p = (const half8*)(hb + gj[k] * 512);
      ga[k][0].v = p[0];
      ga[k][1].v = p[1];
    }
  };
  auto COMBINE = [&](int buf) {
#pragma unroll
    for (int part = 0; part < 2; ++part) {
      GU t0, t1, t2, t3, t4;
#pragma unroll
      for (int j2 = 0; j2 < 4; ++j2) {
        t0.u[j2] = ga[0][part].u[j2] & gm[0];
        t1.u[j2] = ga[1][part].u[j2] & gm[1];
        t2.u[j2] = ga[2][part].u[j2] & gm[2];
        t3.u[j2] = ga[3][part].u[j2] & gm[3];
        t4.u[j2] = ga[4][part].u[j2] & gm[4];
      }
      half8 s = ((t0.v + t1.v) + (t2.v + t3.v)) + t4.v;
      s = s * den8;
      *(half8*)&s_lds[buf][4096 + (2 * gseg + part) * 512 + grow * 8] = s;
    }
  };
  auto STAGE = [&](int buf, int it) {
    int k0 = it << 6;
    const ushort* ph = h16 + (r0 + lane) * 512 + k0 + 8 * wu;
    const ushort* ps = Ws + (c0 + lane) * 512 + k0 + 8 * wu;
    const ushort* pn = Wn + (c0 + lane) * 512 + k0 + 8 * wu;
    ushort* lb = &s_lds[buf][wu << 9];
#define GLDS(SRC, DST) __builtin_amdgcn_global_load_lds( \
      (const __attribute__((address_space(1))) void*)(SRC), \
      (__attribute__((address_space(3))) void*)(DST), 16, 0, 0)
    GLDS(ph, lb);            GLDS(ph + 32, lb + 2048);
    GLDS(ps, lb + 8192);     GLDS(ps + 32, lb + 10240);
    GLDS(pn, lb + 12288);    GLDS(pn + 32, lb + 14336);
#undef GLDS
  };

  f32x16 accS = {}, accN = {};
  GATHER(0);
  STAGE(0, 0);
  COMBINE(0);
  __syncthreads();
  int cur = 0;
  for (int it = 0; it < 8; ++it) {
    if (it < 7) {
      GATHER(it + 1);
      STAGE(cur ^ 1, it + 1);
    }
    const half8* pAh = (const half8*)&s_lds[cur][0];
    const half8* pAg = (const half8*)&s_lds[cur][4096];
    const half8* pBs = (const half8*)&s_lds[cur][8192];
    const half8* pBn = (const half8*)&s_lds[cur][12288];
#pragma unroll
    for (int ks = 0; ks < 4; ++ks) {
      int gi = (2 * ks + hi) * 64;
      half8 ah = pAh[gi + 32 * wr + lo];
      half8 bs = pBs[gi + 32 * wc + lo];
      accS = __builtin_amdgcn_mfma_f32_32x32x16_f16(ah, bs, accS, 0, 0, 0);
      half8 ag = pAg[gi + 32 * wr + lo];
      half8 bn2 = pBn[gi + 32 * wc + lo];
      accN = __builtin_amdgcn_mfma_f32_32x32x16_f16(ag, bn2, accN, 0, 0, 0);
    }
    if (it < 7) COMBINE(cur ^ 1);
    __syncthreads();
    cur ^= 1;
  }

  const int col = c0 + 32 * wc + lo;
  const float b = bias[col];
#pragma unroll
  for (int r = 0; r < 16; ++r) {
    int row = r0 + 32 * wr + (r & 3) + ((r >> 2) << 3) + (hi << 2);
    float v = fmaxf(accS[r] + accN[r] + b, 0.f);
    if (final_layer) fout[row * 512 + col] = v;
    else hout[row * 512 + col] = __builtin_bit_cast(ushort, (_Float16)v);
  }
}

extern "C" void kernel_launch(void* const* d_in, const int* in_sizes, int n_in,
                              void* d_out, int out_size, void* d_ws, size_t ws_size,
                              hipStream_t stream) {
  const float* imgs   = (const float*)d_in[0];
  const float* pos    = (const float*)d_in[1];
  const float* conv_w = (const float*)d_in[2];
  const float* conv_b = (const float*)d_in[3];
  const float* proj_w = (const float*)d_in[4];
  const float* proj_b = (const float*)d_in[5];
  const float* w_self = (const float*)d_in[6];
  const float* w_nbr  = (const float*)d_in[7];
  const float* b_gnn  = (const float*)d_in[8];

  char* ws = (char*)d_ws;
  ushort* wfrag = (ushort*)(ws);
  float*  enc   = (float*) (ws + 32768);
  ushort* h16a  = (ushort*)(ws + 557056);
  ushort* h16b  = (ushort*)(ws + 2654208);
  ushort* wT16  = (ushort*)(ws + 6848512);
  int*    nbr   = (int*)   (ws + 11042816);
  float*  den   = (float*) (ws + 11083776);

  setup_kernel<<<2608, 256, 0, stream>>>(conv_w, w_self, w_nbr, pos,
                                         wfrag, wT16, nbr, den, enc);
  conv_pool_kernel<<<2 * NNODES, 256, 0, stream>>>(imgs, wfrag, conv_b, enc);
  proj_kernel<<<512, 256, 0, stream>>>(enc, proj_w, proj_b, h16a);

  for (int l = 0; l < 4; ++l) {
    ushort* hin  = (l & 1) ? h16b : h16a;
    ushort* hnew = (l & 1) ? h16a : h16b;
    gnn_gemm_kernel<<<256, 256, 0, stream>>>(
        hin, nbr, den, wT16 + l * 262144, wT16 + (4 + l) * 262144,
        b_gnn + l * 512, hnew, (float*)d_out, (l == 3) ? 1 : 0);
  }
}